// Round 7
// baseline (131.926 us; speedup 1.0000x reference)
//
#include <hip/hip_runtime.h>

#define N_NODES 50000
#define E_EDGES 625000
#define D 128
#define NB_M 391          // ceil(N/128)
#define EPB 1600          // edges per gemm block: 391*1600 = 625600 >= E

typedef __attribute__((ext_vector_type(8)))  short  short8;
typedef __attribute__((ext_vector_type(16))) float  floatx16;

static __device__ inline unsigned short f2bf(float f) {
    union { float f; unsigned u; } v; v.f = f;
    unsigned r = v.u + 0x7FFFu + ((v.u >> 16) & 1u);   // RNE
    return (unsigned short)(r >> 16);
}
static __device__ inline float bflo(unsigned p) { return __uint_as_float(p << 16); }
static __device__ inline float bfhi(unsigned p) { return __uint_as_float(p & 0xFFFF0000u); }

// ---------------------------------------------------------------------------
// Kernel 1 (fused): per block --
//  (a) edge slice: meta[e]={src,affine bits}; rowptr[n]=e for n in (dst[e-1],dst[e]]
//  (b) stage bf16 W into 64KB LDS in MFMA-B layout, built straight from
//      global W: coalesced 256B column reads + stride-1 ds_write_b128
//  (c) [Z1b | Y] = bf16(feat @ [W1 | W2]), 32x32x16 bf16 MFMA, 8 sequential
//      col-tiles reusing one 16-reg accumulator; feat read exactly once.
// ---------------------------------------------------------------------------
__global__ __launch_bounds__(256, 2) void gemm_fused(const float* __restrict__ feat,
                                                     const float* __restrict__ W,
                                                     const int* __restrict__ src,
                                                     const int* __restrict__ dst,
                                                     const float* __restrict__ affine,
                                                     int* __restrict__ rowptr,
                                                     uint2* __restrict__ meta,
                                                     unsigned short* __restrict__ Z1b,
                                                     unsigned short* __restrict__ Y) {
    __shared__ short8 Bls[4096];   // 64 KB: slot = h*2048 + c*128 + n

    int tid = threadIdx.x;
    int b   = blockIdx.x;

    // ---- (a) edge slice ----
    {
        int e0 = b * EPB;
        int e1 = e0 + EPB; if (e1 > E_EDGES) e1 = E_EDGES;
        #pragma unroll
        for (int i = 0; i < 7; ++i) {
            int e = e0 + i * 256 + tid;
            if (e < e1) {
                int d1 = dst[e];
                int d0 = (e == 0) ? -1 : dst[e - 1];
                for (int n = d0 + 1; n <= d1; ++n) rowptr[n] = e;
                if (e == E_EDGES - 1)
                    for (int n = d1 + 1; n <= N_NODES; ++n) rowptr[n] = E_EDGES;
                uint2 m;
                m.x = (unsigned)src[e];
                m.y = __float_as_uint(affine[e]);
                meta[e] = m;
            }
        }
    }

    // ---- (b) W -> LDS, final layout, conflict-free ----
    #pragma unroll
    for (int i = 0; i < 16; ++i) {
        int s = tid + i * 256;        // slot 0..4095
        int n = s & 127;
        int c = (s >> 7) & 15;
        int h = s >> 11;
        int krow = h * 128 + c * 8;
        short8 v;
        #pragma unroll
        for (int j = 0; j < 8; ++j)
            v[j] = (short)f2bf(W[(size_t)(krow + j) * D + n]);  // coalesced over n
        Bls[s] = v;                    // stride-1 b128
    }

    // ---- (c) A fragments: feat rows, fp32 -> bf16 in-reg ----
    int wave = tid >> 6;
    int lane = tid & 63;
    int m = lane & 31;
    int g = lane >> 5;
    int row0   = b * 128 + wave * 32;
    int row_a  = row0 + m;
    int rclamp = row_a < N_NODES ? row_a : 0;

    short8 fa[8];
    const float* ap = feat + (size_t)rclamp * D + g * 8;
    #pragma unroll
    for (int ks = 0; ks < 8; ++ks) {
        float4 u = *(const float4*)(ap + ks * 16);
        float4 v = *(const float4*)(ap + ks * 16 + 4);
        short8 a;
        a[0] = (short)f2bf(u.x); a[1] = (short)f2bf(u.y);
        a[2] = (short)f2bf(u.z); a[3] = (short)f2bf(u.w);
        a[4] = (short)f2bf(v.x); a[5] = (short)f2bf(v.y);
        a[6] = (short)f2bf(v.z); a[7] = (short)f2bf(v.w);
        fa[ks] = a;
    }
    __syncthreads();

    #pragma unroll
    for (int t8 = 0; t8 < 8; ++t8) {
        int h = t8 >> 2;
        int n = (t8 & 3) * 32 + m;
        floatx16 acc = {0,0,0,0, 0,0,0,0, 0,0,0,0, 0,0,0,0};
        #pragma unroll
        for (int ks = 0; ks < 8; ++ks) {
            short8 bb = Bls[h * 2048 + (ks * 2 + g) * 128 + n];
            acc = __builtin_amdgcn_mfma_f32_32x32x16_bf16(fa[ks], bb, acc, 0, 0, 0);
        }
        unsigned short* dstbuf = h ? Y : Z1b;
        // D layout: col = lane&31, row = (reg&3) + 8*(reg>>2) + 4*g
        #pragma unroll
        for (int r = 0; r < 16; ++r) {
            int row = row0 + (r & 3) + 8 * (r >> 2) + 4 * g;
            if (row < N_NODES) dstbuf[(size_t)row * D + n] = f2bf(acc[r]);
        }
    }
}

// ---------------------------------------------------------------------------
// Kernel 2: out[n,:] = bf2f(Z1b[n,:]) + bias + sum_e affine[e] * Y[src[e],:]
// One wave per node; quarter g owns edge slot, lane owns 8 features (uint4).
// 16 edges in flight per round, fully predicated; single fp32 write of out.
// ---------------------------------------------------------------------------
__global__ __launch_bounds__(256) void agg_add(const unsigned short* __restrict__ Y,
                                               const unsigned short* __restrict__ Z1b,
                                               const uint2* __restrict__ meta,
                                               const int* __restrict__ rowptr,
                                               const float* __restrict__ bias,
                                               float* __restrict__ out) {
    int wave = threadIdx.x >> 6;
    int lane = threadIdx.x & 63;
    int n = blockIdx.x * 4 + wave;
    if (n >= N_NODES) return;
    int lo = rowptr[n], hi = rowptr[n + 1];
    int g  = lane >> 4;
    int jj = (lane & 15) << 3;
    const unsigned short* Yj = Y + jj;

    float acc[8] = {0,0,0,0,0,0,0,0};

    for (int e0 = lo; e0 < hi; e0 += 16) {
        uint2 md[4];
        #pragma unroll
        for (int u = 0; u < 4; ++u) {
            int i = e0 + u * 4 + g;
            md[u] = meta[i < hi ? i : lo];
        }
        float w[4];
        uint4 p[4];
        #pragma unroll
        for (int u = 0; u < 4; ++u) {
            int i = e0 + u * 4 + g;
            w[u] = (i < hi) ? __uint_as_float(md[u].y) : 0.f;
            p[u] = *(const uint4*)(Yj + (size_t)md[u].x * D);
        }
        #pragma unroll
        for (int u = 0; u < 4; ++u) {
            acc[0] += bflo(p[u].x) * w[u];  acc[1] += bfhi(p[u].x) * w[u];
            acc[2] += bflo(p[u].y) * w[u];  acc[3] += bfhi(p[u].y) * w[u];
            acc[4] += bflo(p[u].z) * w[u];  acc[5] += bfhi(p[u].z) * w[u];
            acc[6] += bflo(p[u].w) * w[u];  acc[7] += bfhi(p[u].w) * w[u];
        }
    }

    #pragma unroll
    for (int r = 0; r < 8; ++r) {
        acc[r] += __shfl_xor(acc[r], 16);
        acc[r] += __shfl_xor(acc[r], 32);
    }

    if (g == 0) {
        uint4  z  = *(const uint4*)(Z1b + (size_t)n * D + jj);
        float4 b0 = *(const float4*)(bias + jj);
        float4 b1 = *(const float4*)(bias + jj + 4);
        float* op = out + (size_t)n * D + jj;
        float4 o0, o1;
        o0.x = bflo(z.x) + b0.x + acc[0];  o0.y = bfhi(z.x) + b0.y + acc[1];
        o0.z = bflo(z.y) + b0.z + acc[2];  o0.w = bfhi(z.y) + b0.w + acc[3];
        o1.x = bflo(z.z) + b1.x + acc[4];  o1.y = bfhi(z.z) + b1.y + acc[5];
        o1.z = bflo(z.w) + b1.z + acc[6];  o1.w = bfhi(z.w) + b1.w + acc[7];
        *(float4*)op       = o0;
        *(float4*)(op + 4) = o1;
    }
}

// ---------------------------------------------------------------------------
extern "C" void kernel_launch(void* const* d_in, const int* in_sizes, int n_in,
                              void* d_out, int out_size, void* d_ws, size_t ws_size,
                              hipStream_t stream) {
    const float* feat   = (const float*)d_in[0];
    const float* affine = (const float*)d_in[1];
    const int*   src    = (const int*)  d_in[2];
    const int*   dst    = (const int*)  d_in[3];
    const float* W      = (const float*)d_in[4];
    const float* bias   = (const float*)d_in[5];
    float*       out    = (float*)d_out;

    // ws: rowptr 256KB @0; meta 5MB @262144; Y 12.8MB @5262144;
    //     Z1b 12.8MB @18062144.
    int*            rowptr = (int*)d_ws;
    uint2*          meta   = (uint2*)((char*)d_ws + 262144);
    unsigned short* Y      = (unsigned short*)((char*)d_ws + 5262144);
    unsigned short* Z1b    = (unsigned short*)((char*)d_ws + 18062144);

    gemm_fused<<<NB_M, 256, 0, stream>>>(feat, W, src, dst, affine,
                                         rowptr, meta, Z1b, Y);
    agg_add<<<(N_NODES + 3) / 4, 256, 0, stream>>>(Y, Z1b, meta, rowptr, bias, out);
}

// Round 8
// 126.182 us; speedup vs baseline: 1.0455x; 1.0455x over previous
//
#include <hip/hip_runtime.h>

#define N_NODES 50000
#define E_EDGES 625000
#define D 128

typedef __attribute__((ext_vector_type(8)))  short  short8;
typedef __attribute__((ext_vector_type(16))) float  floatx16;

static __device__ inline unsigned short f2bf(float f) {
    union { float f; unsigned u; } v; v.f = f;
    unsigned r = v.u + 0x7FFFu + ((v.u >> 16) & 1u);   // RNE
    return (unsigned short)(r >> 16);
}
static __device__ inline float bflo(unsigned p) { return __uint_as_float(p << 16); }
static __device__ inline float bfhi(unsigned p) { return __uint_as_float(p & 0xFFFF0000u); }

// ---------------------------------------------------------------------------
// Kernel 1 (prep), edge-parallel / streaming, O(1) load-chain depth:
//  - rowptr: thread t writes rowptr[n]=t for n in (dst[t-1], dst[t]]
//  - meta[e] = {src[e], bits(affine[e])}
//  - bf16 W image in final LDS layout (slot t = h*2048+c*128+n holds
//    W[h*128+c*8+j][n], j=0..7)
// ---------------------------------------------------------------------------
__global__ __launch_bounds__(256) void prep_kernel(const int* __restrict__ dst,
                                                   const float* __restrict__ W,
                                                   const int* __restrict__ src,
                                                   const float* __restrict__ affine,
                                                   int* __restrict__ rowptr,
                                                   unsigned short* __restrict__ wimg,
                                                   uint2* __restrict__ meta) {
    int t = blockIdx.x * 256 + threadIdx.x;
    if (t < E_EDGES) {
        int d1 = dst[t];
        int d0 = (t == 0) ? -1 : dst[t - 1];
        for (int n = d0 + 1; n <= d1; ++n) rowptr[n] = t;
        if (t == E_EDGES - 1)
            for (int n = d1 + 1; n <= N_NODES; ++n) rowptr[n] = E_EDGES;
        uint2 m;
        m.x = (unsigned)src[t];
        m.y = __float_as_uint(affine[t]);
        meta[t] = m;
    }
    if (t < 4096) {
        int n = t & 127;
        int c = (t >> 7) & 15;
        int h = t >> 11;
        int krow = h * 128 + c * 8;
        short8 v;
        #pragma unroll
        for (int j = 0; j < 8; ++j)
            v[j] = (short)f2bf(W[(size_t)(krow + j) * D + n]);
        *((short8*)wimg + t) = v;
    }
}

// ---------------------------------------------------------------------------
// Kernel 2: [Z1b | Y] = bf16(feat @ [W1 | W2]) with 32x32x16 bf16 MFMA.
// h selects the W half; both halves store bf16 (bias deferred to agg).
// XCD-pairing swizzle keeps the (b,h) pair on one XCD for feat L2 reuse.
// 32 KB LDS, 3 blocks/CU.
// ---------------------------------------------------------------------------
#define NB_M 391   // ceil(N/128)

__global__ __launch_bounds__(256, 3) void gemm_mfma(const float* __restrict__ feat,
                                                    const unsigned short* __restrict__ wimg,
                                                    unsigned short* __restrict__ Z1b,
                                                    unsigned short* __restrict__ Y) {
    __shared__ short8 Bls[2048];   // 32 KB

    int tid = threadIdx.x;
    int idx = blockIdx.x;
    int h   = (idx >> 3) & 1;
    int b   = ((idx >> 4) << 3) | (idx & 7);
    if (b >= NB_M) return;

    const short8* wsrc = (const short8*)wimg + h * 2048;
    #pragma unroll
    for (int i = 0; i < 8; ++i)
        Bls[tid + i * 256] = wsrc[tid + i * 256];

    int wave = tid >> 6;
    int lane = tid & 63;
    int m = lane & 31;
    int g = lane >> 5;
    int row0   = b * 128 + wave * 32;
    int row_a  = row0 + m;
    int rclamp = row_a < N_NODES ? row_a : 0;

    short8 fa[8];
    const float* ap = feat + (size_t)rclamp * D + g * 8;
    #pragma unroll
    for (int ks = 0; ks < 8; ++ks) {
        float4 u = *(const float4*)(ap + ks * 16);
        float4 v = *(const float4*)(ap + ks * 16 + 4);
        short8 a;
        a[0] = (short)f2bf(u.x); a[1] = (short)f2bf(u.y);
        a[2] = (short)f2bf(u.z); a[3] = (short)f2bf(u.w);
        a[4] = (short)f2bf(v.x); a[5] = (short)f2bf(v.y);
        a[6] = (short)f2bf(v.z); a[7] = (short)f2bf(v.w);
        fa[ks] = a;
    }
    __syncthreads();

    unsigned short* dstbuf = h ? Y : Z1b;

    #pragma unroll
    for (int t4 = 0; t4 < 4; ++t4) {
        int n = t4 * 32 + m;
        floatx16 acc = {0,0,0,0, 0,0,0,0, 0,0,0,0, 0,0,0,0};
        #pragma unroll
        for (int ks = 0; ks < 8; ++ks) {
            short8 bb = Bls[(ks * 2 + g) * 128 + n];
            acc = __builtin_amdgcn_mfma_f32_32x32x16_bf16(fa[ks], bb, acc, 0, 0, 0);
        }
        // D layout: col = lane&31, row = (reg&3) + 8*(reg>>2) + 4*g
        #pragma unroll
        for (int r = 0; r < 16; ++r) {
            int row = row0 + (r & 3) + 8 * (r >> 2) + 4 * g;
            if (row < N_NODES) dstbuf[(size_t)row * D + n] = f2bf(acc[r]);
        }
    }
}

// ---------------------------------------------------------------------------
// Kernel 3: out[n,:] = bf2f(Z1b[n,:]) + bias + sum_e affine[e] * Y[src[e],:]
// One wave per node; quarter g owns edge slot, lane owns 8 features (uint4).
// 16 edges in flight per round, fully predicated. Z1b/bias loads hoisted
// ABOVE the gather loop so their latency overlaps the edge gathers.
// ---------------------------------------------------------------------------
__global__ __launch_bounds__(256) void agg_add(const unsigned short* __restrict__ Y,
                                               const unsigned short* __restrict__ Z1b,
                                               const uint2* __restrict__ meta,
                                               const int* __restrict__ rowptr,
                                               const float* __restrict__ bias,
                                               float* __restrict__ out) {
    int wave = threadIdx.x >> 6;
    int lane = threadIdx.x & 63;
    int n = blockIdx.x * 4 + wave;
    if (n >= N_NODES) return;
    int lo = rowptr[n], hi = rowptr[n + 1];
    int g  = lane >> 4;
    int jj = (lane & 15) << 3;
    const unsigned short* Yj = Y + jj;

    // Epilogue operands issued early — overlap with the gather chain below.
    uint4  z  = *(const uint4*)(Z1b + (size_t)n * D + jj);
    float4 b0 = *(const float4*)(bias + jj);
    float4 b1 = *(const float4*)(bias + jj + 4);

    float acc[8] = {0,0,0,0,0,0,0,0};

    for (int e0 = lo; e0 < hi; e0 += 16) {
        uint2 md[4];
        #pragma unroll
        for (int u = 0; u < 4; ++u) {
            int i = e0 + u * 4 + g;
            md[u] = meta[i < hi ? i : lo];
        }
        float w[4];
        uint4 p[4];
        #pragma unroll
        for (int u = 0; u < 4; ++u) {
            int i = e0 + u * 4 + g;
            w[u] = (i < hi) ? __uint_as_float(md[u].y) : 0.f;
            p[u] = *(const uint4*)(Yj + (size_t)md[u].x * D);
        }
        #pragma unroll
        for (int u = 0; u < 4; ++u) {
            acc[0] += bflo(p[u].x) * w[u];  acc[1] += bfhi(p[u].x) * w[u];
            acc[2] += bflo(p[u].y) * w[u];  acc[3] += bfhi(p[u].y) * w[u];
            acc[4] += bflo(p[u].z) * w[u];  acc[5] += bfhi(p[u].z) * w[u];
            acc[6] += bflo(p[u].w) * w[u];  acc[7] += bfhi(p[u].w) * w[u];
        }
    }

    #pragma unroll
    for (int r = 0; r < 8; ++r) {
        acc[r] += __shfl_xor(acc[r], 16);
        acc[r] += __shfl_xor(acc[r], 32);
    }

    if (g == 0) {
        float* op = out + (size_t)n * D + jj;
        float4 o0, o1;
        o0.x = bflo(z.x) + b0.x + acc[0];  o0.y = bfhi(z.x) + b0.y + acc[1];
        o0.z = bflo(z.y) + b0.z + acc[2];  o0.w = bfhi(z.y) + b0.w + acc[3];
        o1.x = bflo(z.z) + b1.x + acc[4];  o1.y = bfhi(z.z) + b1.y + acc[5];
        o1.z = bflo(z.w) + b1.z + acc[6];  o1.w = bfhi(z.w) + b1.w + acc[7];
        *(float4*)op       = o0;
        *(float4*)(op + 4) = o1;
    }
}

// ---------------------------------------------------------------------------
extern "C" void kernel_launch(void* const* d_in, const int* in_sizes, int n_in,
                              void* d_out, int out_size, void* d_ws, size_t ws_size,
                              hipStream_t stream) {
    const float* feat   = (const float*)d_in[0];
    const float* affine = (const float*)d_in[1];
    const int*   src    = (const int*)  d_in[2];
    const int*   dst    = (const int*)  d_in[3];
    const float* W      = (const float*)d_in[4];
    const float* bias   = (const float*)d_in[5];
    float*       out    = (float*)d_out;

    // ws: wimg 64KB @0; rowptr @64K; meta 5MB @266240; Y 12.8MB @5267456;
    //     Z1b 12.8MB @18067456.
    unsigned short* wimg   = (unsigned short*)d_ws;
    int*            rowptr = (int*)((char*)d_ws + 65536);
    uint2*          meta   = (uint2*)((char*)d_ws + 266240);
    unsigned short* Y      = (unsigned short*)((char*)d_ws + 5267456);
    unsigned short* Z1b    = (unsigned short*)((char*)d_ws + 18067456);

    prep_kernel<<<(E_EDGES + 255) / 256, 256, 0, stream>>>(dst, W, src, affine,
                                                           rowptr, wimg, meta);
    int gemm_blocks = ((2 * NB_M + 15) / 16) * 16;
    gemm_mfma<<<gemm_blocks, 256, 0, stream>>>(feat, wimg, Z1b, Y);
    agg_add<<<(N_NODES + 3) / 4, 256, 0, stream>>>(Y, Z1b, meta, rowptr, bias, out);
}